// Round 14
// baseline (212.261 us; speedup 1.0000x reference)
//
#include <hip/hip_runtime.h>
#include <math.h>

#define NN 8192
#define KDIM 512
#define DD 256
#define CS 32      // prefix chunk size
#define NC 256     // number of chunks
#define BM 128     // gemm tile rows
#define BN 64      // gemm tile cols

typedef float4 f4;
typedef __attribute__((ext_vector_type(4))) float f4v;  // native vec for nontemporal

__device__ __forceinline__ float dot4(const f4& x, const f4& y) {
  return x.x * y.x + x.y * y.y + x.z * y.z + x.w * y.w;
}

// ---------- K1: H = X @ W (f32 vector GEMM, 128x64 tile) + s,t tail ----------
// K-order per output element identical to the 64x64 version -> H bitwise same.
__global__ __launch_bounds__(256) void k_gemm(const float* __restrict__ X,
                                              const float* __restrict__ W,
                                              const float* __restrict__ av,
                                              float* __restrict__ H,
                                              float* __restrict__ s,
                                              float* __restrict__ t) {
  __shared__ float Xs[32][BM];  // 16 KB, [k][r] transposed; reused as wv1/wv2
  __shared__ float Ws[32][BN];  // 8 KB
  const int tid = threadIdx.x;
  const int tx = tid & 15;      // col group -> 4 cols
  const int ty = tid >> 4;      // row group -> 8 rows
  const int r0 = blockIdx.x * BM;
  const int c0 = blockIdx.y * BN;
  float acc[8][4] = {};
  for (int k0 = 0; k0 < KDIM; k0 += 32) {
#pragma unroll
    for (int q = 0; q < 4; ++q) {
      int fi = tid + q * 256;      // X tile: 128 rows x 8 f4
      int r = fi >> 3;
      int kq = fi & 7;
      f4 v = *reinterpret_cast<const f4*>(&X[(size_t)(r0 + r) * KDIM + k0 + kq * 4]);
      Xs[kq * 4 + 0][r] = v.x; Xs[kq * 4 + 1][r] = v.y;
      Xs[kq * 4 + 2][r] = v.z; Xs[kq * 4 + 3][r] = v.w;
    }
#pragma unroll
    for (int q = 0; q < 2; ++q) {
      int fi = tid + q * 256;      // W tile: 32 k x 16 f4
      int k = fi >> 4;
      int cq = fi & 15;
      *reinterpret_cast<f4*>(&Ws[k][cq * 4]) =
          *reinterpret_cast<const f4*>(&W[(size_t)(k0 + k) * DD + c0 + cq * 4]);
    }
    __syncthreads();
#pragma unroll
    for (int k = 0; k < 32; ++k) {
      f4 xa = *reinterpret_cast<const f4*>(&Xs[k][ty * 8]);
      f4 xb = *reinterpret_cast<const f4*>(&Xs[k][ty * 8 + 4]);
      f4 wv = *reinterpret_cast<const f4*>(&Ws[k][tx * 4]);
      float xs[8] = {xa.x, xa.y, xa.z, xa.w, xb.x, xb.y, xb.z, xb.w};
      float ws[4] = {wv.x, wv.y, wv.z, wv.w};
#pragma unroll
      for (int i = 0; i < 8; ++i)
#pragma unroll
        for (int j = 0; j < 4; ++j) acc[i][j] += xs[i] * ws[j];
    }
    __syncthreads();
  }
#pragma unroll
  for (int i = 0; i < 8; ++i) {
    f4 v = {acc[i][0], acc[i][1], acc[i][2], acc[i][3]};
    *reinterpret_cast<f4*>(&H[(size_t)(r0 + ty * 8 + i) * DD + c0 + tx * 4]) = v;
  }

  if (c0 == 0) {
    // s,t for rows r0..r0+127 via s = X@(W@a1), t = X@(W@a2)
    int wid = tid >> 6, lane = tid & 63;
    float* wv1 = &Xs[0][0];        // [512]
    float* wv2 = &Xs[0][0] + 512;  // [512]
    for (int k = tid; k < KDIM; k += 256) {
      float a1acc = 0.f, a2acc = 0.f;
#pragma unroll 8
      for (int d4 = 0; d4 < DD / 4; ++d4) {
        f4 wrow = *reinterpret_cast<const f4*>(&W[(size_t)k * DD + d4 * 4]);
        f4 a1v = *reinterpret_cast<const f4*>(&av[d4 * 4]);
        f4 a2v = *reinterpret_cast<const f4*>(&av[DD + d4 * 4]);
        a1acc += dot4(wrow, a1v);
        a2acc += dot4(wrow, a2v);
      }
      wv1[k] = a1acc;
      wv2[k] = a2acc;
    }
    __syncthreads();
    f4 w1a = *reinterpret_cast<const f4*>(&wv1[lane * 8]);
    f4 w1b = *reinterpret_cast<const f4*>(&wv1[lane * 8 + 4]);
    f4 w2a = *reinterpret_cast<const f4*>(&wv2[lane * 8]);
    f4 w2b = *reinterpret_cast<const f4*>(&wv2[lane * 8 + 4]);
    for (int rr = 0; rr < 32; ++rr) {
      int i = r0 + wid * 32 + rr;
      f4 xa = *reinterpret_cast<const f4*>(&X[(size_t)i * KDIM + lane * 8]);
      f4 xb = *reinterpret_cast<const f4*>(&X[(size_t)i * KDIM + lane * 8 + 4]);
      float p1 = dot4(xa, w1a) + dot4(xb, w1b);
      float p2 = dot4(xa, w2a) + dot4(xb, w2b);
      for (int off = 32; off > 0; off >>= 1) {
        p1 += __shfl_down(p1, off);
        p2 += __shfl_down(p2, off);
      }
      if (lane == 0) { s[i] = p1; t[i] = p2; }
    }
  }
}

// ---------- K2: tmax, E/c (16 rows), rank 16 keys + ki-count 16 rows ----------
__global__ __launch_bounds__(256) void k_mid(const float* __restrict__ s,
                                             const float* __restrict__ t,
                                             float* __restrict__ E1,
                                             float* __restrict__ E2,
                                             float* __restrict__ c1,
                                             float* __restrict__ c2,
                                             int* __restrict__ perm,
                                             float* __restrict__ Es1,
                                             float* __restrict__ Es2,
                                             int* __restrict__ kidx) {
  __shared__ float lred[4];
  const int b = blockIdx.x, tid = threadIdx.x;
  const int wid = tid >> 6, lane = tid & 63;
  float m = -1e30f;
#pragma unroll
  for (int q = 0; q < 8; ++q) {
    int idx = (q * 256 + tid) * 4;
    f4 v = *reinterpret_cast<const f4*>(&t[idx]);
    m = fmaxf(m, fmaxf(fmaxf(v.x, v.y), fmaxf(v.z, v.w)));
  }
  for (int off = 32; off > 0; off >>= 1) m = fmaxf(m, __shfl_down(m, off));
  if (lane == 0) lred[wid] = m;
  __syncthreads();
  float tmax = fmaxf(fmaxf(lred[0], lred[1]), fmaxf(lred[2], lred[3]));

  if (tid < 16) {
    int i = b * 16 + tid;
    float ti = t[i];
    E1[i] = expf(ti);
    E2[i] = expf(0.2f * ti);
    float si = s[i];
    float e = si + tmax;
    float mm = e > 0.f ? e : 0.2f * e;
    c1[i] = expf(si - mm);
    c2[i] = expf(0.2f * si - mm);
  }

  // 4 rank keys + 4 s-keys per wave (wave-uniform keys, per-lane value slices)
  float tkv[4], skv[4]; int jj[4], cnt[4], cntk[4];
#pragma unroll
  for (int q = 0; q < 4; ++q) {
    jj[q] = b * 16 + wid * 4 + q;
    tkv[q] = t[jj[q]];
    skv[q] = -s[jj[q]];
    cnt[q] = 0;
    cntk[q] = 0;
  }
  for (int m2 = 0; m2 < 32; ++m2) {
    int i4 = m2 * 64 + lane;
    f4 v = *reinterpret_cast<const f4*>(&t[i4 * 4]);
    int base = i4 * 4;
#pragma unroll
    for (int q = 0; q < 4; ++q) {
      cnt[q] += (v.x < tkv[q]) || (v.x == tkv[q] && base + 0 < jj[q]);
      cnt[q] += (v.y < tkv[q]) || (v.y == tkv[q] && base + 1 < jj[q]);
      cnt[q] += (v.z < tkv[q]) || (v.z == tkv[q] && base + 2 < jj[q]);
      cnt[q] += (v.w < tkv[q]) || (v.w == tkv[q] && base + 3 < jj[q]);
      cntk[q] += (v.x <= skv[q]) + (v.y <= skv[q]) + (v.z <= skv[q]) + (v.w <= skv[q]);
    }
  }
#pragma unroll
  for (int q = 0; q < 4; ++q) {
    int c = cnt[q], ck = cntk[q];
    for (int off = 32; off > 0; off >>= 1) {
      c += __shfl_down(c, off);
      ck += __shfl_down(ck, off);
    }
    if (lane == 0) {
      perm[c] = jj[q];
      Es1[c] = expf(tkv[q]);        // bitwise == E1[jj[q]]
      Es2[c] = expf(0.2f * tkv[q]);
      kidx[jj[q]] = ck;
    }
  }
}

// ---------- K3: per-chunk totals of Es*H(perm) over sorted order ----------
__global__ __launch_bounds__(256) void k_chunk(const float* __restrict__ H,
                                               const float* __restrict__ Es1,
                                               const float* __restrict__ Es2,
                                               const int* __restrict__ perm,
                                               float* __restrict__ Ctot1,
                                               float* __restrict__ Ctot2,
                                               float* __restrict__ cs1,
                                               float* __restrict__ cs2) {
  __shared__ int pms[CS];
  int c = blockIdx.x;
  int d = threadIdx.x;
  if (d < CS) pms[d] = perm[c * CS + d];
  __syncthreads();
  float s1 = 0.f, s2 = 0.f, a1 = 0.f, a2 = 0.f;
#pragma unroll 4
  for (int kk = 0; kk < CS; ++kk) {
    int mI = c * CS + kk;
    float e1 = Es1[mI], e2 = Es2[mI];
    float h = H[(size_t)pms[kk] * DD + d];
    s1 += e1 * h; s2 += e2 * h;
    a1 += e1;     a2 += e2;
  }
  Ctot1[c * DD + d] = s1;
  Ctot2[c * DD + d] = s2;
  if (d == 0) { cs1[c] = a1; cs2[c] = a2; }
}

// ---------- K4: Cpre (triangular, pipelined) + scalar scan + f1/f2 ----------
__global__ __launch_bounds__(256) void k_scan(const float* __restrict__ Ctot1,
                                              const float* __restrict__ Ctot2,
                                              const float* __restrict__ cs1,
                                              const float* __restrict__ cs2,
                                              const float* __restrict__ Es1,
                                              const float* __restrict__ Es2,
                                              const int* __restrict__ kidx,
                                              const float* __restrict__ c1,
                                              const float* __restrict__ c2,
                                              float* __restrict__ Cpre1,
                                              float* __restrict__ Cpre2,
                                              float* __restrict__ f1,
                                              float* __restrict__ f2) {
  __shared__ float sc1[NC], sc2[NC];
  const int c = blockIdx.x;
  const int d = threadIdx.x;
  float r1a = 0.f, r1b = 0.f, r2a = 0.f, r2b = 0.f;
  int cc = 0;
  for (; cc + 4 <= c; cc += 4) {
    r1a += Ctot1[(cc + 0) * DD + d];
    r1b += Ctot1[(cc + 1) * DD + d];
    r1a += Ctot1[(cc + 2) * DD + d];
    r1b += Ctot1[(cc + 3) * DD + d];
    r2a += Ctot2[(cc + 0) * DD + d];
    r2b += Ctot2[(cc + 1) * DD + d];
    r2a += Ctot2[(cc + 2) * DD + d];
    r2b += Ctot2[(cc + 3) * DD + d];
  }
  for (; cc < c; ++cc) {
    r1a += Ctot1[cc * DD + d];
    r2a += Ctot2[cc * DD + d];
  }
  float r1 = r1a + r1b, r2 = r2a + r2b;
  Cpre1[(size_t)c * DD + d] = r1;
  Cpre2[(size_t)c * DD + d] = r2;
  if (c == NC - 1) {
    Cpre1[(size_t)NC * DD + d] = r1 + Ctot1[c * DD + d];
    Cpre2[(size_t)NC * DD + d] = r2 + Ctot2[c * DD + d];
  }
  sc1[d] = cs1[d];
  sc2[d] = cs2[d];
  __syncthreads();
  for (int off = 1; off < NC; off <<= 1) {
    float y1 = (d >= off) ? sc1[d - off] : 0.f;
    float y2 = (d >= off) ? sc2[d - off] : 0.f;
    __syncthreads();
    sc1[d] += y1; sc2[d] += y2;
    __syncthreads();
  }
  if (d < 32) {
    int i = c * 32 + d;
    int ki = kidx[i];
    int ci = ki >> 5;
    float sp1 = ci ? sc1[ci - 1] : 0.f;
    float sp2 = ci ? sc2[ci - 1] : 0.f;
    for (int m = ci * CS; m < ki; ++m) { sp1 += Es1[m]; sp2 += Es2[m]; }
    float T1s = sc1[NC - 1];
    float a1 = c1[i], a2 = c2[i];
    float Z = a1 * (T1s - sp1) + a2 * sp2;
    float rZ = 1.0f / Z;
    f1[i] = rZ * a1;
    f2[i] = rZ * a2;
  }
}

// ---------- K5: merged finalize (4 rows) + A-stream tile (2048 blocks) -------
__global__ __launch_bounds__(256) void k_finstream(const int* __restrict__ kidx,
                                                   const float* __restrict__ Es1,
                                                   const float* __restrict__ Es2,
                                                   const int* __restrict__ perm,
                                                   const float* __restrict__ H,
                                                   const float* __restrict__ Cpre1,
                                                   const float* __restrict__ Cpre2,
                                                   const float* __restrict__ f1,
                                                   const float* __restrict__ f2,
                                                   float* __restrict__ out,
                                                   const float* __restrict__ s,
                                                   const float* __restrict__ t,
                                                   const float* __restrict__ E1,
                                                   const float* __restrict__ E2,
                                                   float* __restrict__ A) {
  const int bb = blockIdx.x;
  const int d = threadIdx.x;
  // ---- finalize rows bb*4..bb*4+3 ----
  {
    float T1 = Cpre1[(size_t)NC * DD + d];
#pragma unroll
    for (int r = 0; r < 4; ++r) {
      int i = bb * 4 + r;
      int ki = kidx[i];
      int ci = ki >> 5;
      float P1 = Cpre1[(size_t)ci * DD + d];
      float P2 = Cpre2[(size_t)ci * DD + d];
      for (int m = ci * CS; m < ki; ++m) {
        float h = H[(size_t)perm[m] * DD + d];
        P1 += Es1[m] * h;
        P2 += Es2[m] * h;
      }
      out[(size_t)i * DD + d] = f1[i] * (T1 - P1) + f2[i] * P2;
    }
  }
  // ---- A-stream tile: rows (bb>>3)*32.., cols (bb&7)*1024.. ----
  {
    int i0 = (bb >> 3) * 32;
    int j0 = (bb & 7) * 1024 + d * 4;
    f4 t4  = *reinterpret_cast<const f4*>(&t[j0]);
    f4 e14 = *reinterpret_cast<const f4*>(&E1[j0]);
    f4 e24 = *reinterpret_cast<const f4*>(&E2[j0]);
#pragma unroll 4
    for (int rr = 0; rr < 32; ++rr) {
      int i = i0 + rr;
      float ss = s[i], ff1 = f1[i], ff2 = f2[i];
      f4v o;
      float e;
      e = ss + t4.x; o.x = (e > 0.f) ? ff1 * e14.x : ff2 * e24.x;
      e = ss + t4.y; o.y = (e > 0.f) ? ff1 * e14.y : ff2 * e24.y;
      e = ss + t4.z; o.z = (e > 0.f) ? ff1 * e14.z : ff2 * e24.z;
      e = ss + t4.w; o.w = (e > 0.f) ? ff1 * e14.w : ff2 * e24.w;
      __builtin_nontemporal_store(o, reinterpret_cast<f4v*>(&A[(size_t)i * NN + j0]));
    }
  }
}

extern "C" void kernel_launch(void* const* d_in, const int* in_sizes, int n_in,
                              void* d_out, int out_size, void* d_ws, size_t ws_size,
                              hipStream_t stream) {
  const float* X  = (const float*)d_in[0];
  const float* W  = (const float*)d_in[1];
  const float* av = (const float*)d_in[2];
  float* outp = (float*)d_out;                  // [NN*DD]
  float* A = outp + (size_t)NN * DD;            // [NN*NN]
  float* wsp = (float*)d_ws;

  // ws layout (floats); total 2,490,368 floats = 9.96 MB (proven fit in R11)
  float* s     = wsp + 0;
  float* t     = wsp + 8192;
  float* E1    = wsp + 16384;
  float* E2    = wsp + 24576;
  float* c1    = wsp + 32768;
  float* c2    = wsp + 40960;
  float* f1    = wsp + 49152;
  float* f2    = wsp + 57344;
  float* Ctot1 = wsp + 65536;     // 65536
  float* Ctot2 = wsp + 131072;    // 65536
  float* Cpre1 = wsp + 196608;    // 65792 (257*256)
  float* Cpre2 = wsp + 262400;    // 65792
  float* cs1   = wsp + 328192;    // 256
  float* cs2   = wsp + 328448;    // 256
  float* Es1   = wsp + 328704;    // 8192
  float* Es2   = wsp + 336896;    // 8192
  int*   kidx  = (int*)(wsp + 345088);  // 8192
  int*   perm  = (int*)(wsp + 353280);  // 8192
  float* H     = wsp + 393216;    // 2097152

  k_gemm<<<dim3(NN / BM, DD / BN), 256, 0, stream>>>(X, W, av, H, s, t);
  k_mid<<<NN / 16, 256, 0, stream>>>(s, t, E1, E2, c1, c2, perm, Es1, Es2, kidx);
  k_chunk<<<NC, 256, 0, stream>>>(H, Es1, Es2, perm, Ctot1, Ctot2, cs1, cs2);
  k_scan<<<NC, 256, 0, stream>>>(Ctot1, Ctot2, cs1, cs2, Es1, Es2, kidx, c1, c2,
                                 Cpre1, Cpre2, f1, f2);
  k_finstream<<<NN / 4, 256, 0, stream>>>(kidx, Es1, Es2, perm, H, Cpre1, Cpre2,
                                          f1, f2, outp, s, t, E1, E2, A);
}

// Round 15
// 182.993 us; speedup vs baseline: 1.1599x; 1.1599x over previous
//
#include <hip/hip_runtime.h>
#include <math.h>

#define NN 8192
#define KDIM 512
#define DD 256
#define CS 32      // prefix chunk size
#define NC 256     // number of chunks

typedef float4 f4;
typedef __attribute__((ext_vector_type(4))) float f4v;  // native vec for nontemporal

__device__ __forceinline__ float dot4(const f4& x, const f4& y) {
  return x.x * y.x + x.y * y.y + x.z * y.z + x.w * y.w;
}

// ---------- K1: H = X @ W (f32 vector GEMM, 64x64 tile) + s,t tail ----------
__global__ __launch_bounds__(256) void k_gemm(const float* __restrict__ X,
                                              const float* __restrict__ W,
                                              const float* __restrict__ av,
                                              float* __restrict__ H,
                                              float* __restrict__ s,
                                              float* __restrict__ t) {
  __shared__ float Xs[32][64];  // [k][r] (transposed); reused as wv1/wv2 after
  __shared__ float Ws[32][64];  // [k][c]
  const int tid = threadIdx.x;
  const int tx = tid & 15;
  const int ty = tid >> 4;
  const int r0 = blockIdx.x * 64;
  const int c0 = blockIdx.y * 64;
  float acc[4][4] = {};
  for (int k0 = 0; k0 < KDIM; k0 += 32) {
#pragma unroll
    for (int q = 0; q < 2; ++q) {
      int fi = tid + q * 256;
      int r = fi >> 3;
      int kq = fi & 7;
      f4 v = *reinterpret_cast<const f4*>(&X[(size_t)(r0 + r) * KDIM + k0 + kq * 4]);
      Xs[kq * 4 + 0][r] = v.x; Xs[kq * 4 + 1][r] = v.y;
      Xs[kq * 4 + 2][r] = v.z; Xs[kq * 4 + 3][r] = v.w;
    }
#pragma unroll
    for (int q = 0; q < 2; ++q) {
      int fi = tid + q * 256;
      int k = fi >> 4;
      int cq = fi & 15;
      *reinterpret_cast<f4*>(&Ws[k][cq * 4]) =
          *reinterpret_cast<const f4*>(&W[(size_t)(k0 + k) * DD + c0 + cq * 4]);
    }
    __syncthreads();
#pragma unroll
    for (int k = 0; k < 32; ++k) {
      f4 xv = *reinterpret_cast<const f4*>(&Xs[k][ty * 4]);
      f4 wv = *reinterpret_cast<const f4*>(&Ws[k][tx * 4]);
      float xs[4] = {xv.x, xv.y, xv.z, xv.w};
      float ws[4] = {wv.x, wv.y, wv.z, wv.w};
#pragma unroll
      for (int i = 0; i < 4; ++i)
#pragma unroll
        for (int j = 0; j < 4; ++j) acc[i][j] += xs[i] * ws[j];
    }
    __syncthreads();
  }
#pragma unroll
  for (int i = 0; i < 4; ++i) {
    f4 v = {acc[i][0], acc[i][1], acc[i][2], acc[i][3]};
    *reinterpret_cast<f4*>(&H[(size_t)(r0 + ty * 4 + i) * DD + c0 + tx * 4]) = v;
  }

  if (c0 == 0) {
    // s,t for rows r0..r0+63 via s = X@(W@a1), t = X@(W@a2)
    int wid = tid >> 6, lane = tid & 63;
    float* wv1 = &Xs[0][0];        // [512]
    float* wv2 = &Xs[0][0] + 512;  // [512]
    for (int k = tid; k < KDIM; k += 256) {
      float a1acc = 0.f, a2acc = 0.f;
#pragma unroll 8
      for (int d4 = 0; d4 < DD / 4; ++d4) {
        f4 wrow = *reinterpret_cast<const f4*>(&W[(size_t)k * DD + d4 * 4]);
        f4 a1v = *reinterpret_cast<const f4*>(&av[d4 * 4]);
        f4 a2v = *reinterpret_cast<const f4*>(&av[DD + d4 * 4]);
        a1acc += dot4(wrow, a1v);
        a2acc += dot4(wrow, a2v);
      }
      wv1[k] = a1acc;
      wv2[k] = a2acc;
    }
    __syncthreads();
    f4 w1a = *reinterpret_cast<const f4*>(&wv1[lane * 8]);
    f4 w1b = *reinterpret_cast<const f4*>(&wv1[lane * 8 + 4]);
    f4 w2a = *reinterpret_cast<const f4*>(&wv2[lane * 8]);
    f4 w2b = *reinterpret_cast<const f4*>(&wv2[lane * 8 + 4]);
    for (int rr = 0; rr < 16; ++rr) {
      int i = r0 + wid * 16 + rr;
      f4 xa = *reinterpret_cast<const f4*>(&X[(size_t)i * KDIM + lane * 8]);
      f4 xb = *reinterpret_cast<const f4*>(&X[(size_t)i * KDIM + lane * 8 + 4]);
      float p1 = dot4(xa, w1a) + dot4(xb, w1b);
      float p2 = dot4(xa, w2a) + dot4(xb, w2b);
      for (int off = 32; off > 0; off >>= 1) {
        p1 += __shfl_down(p1, off);
        p2 += __shfl_down(p2, off);
      }
      if (lane == 0) { s[i] = p1; t[i] = p2; }
    }
  }
}

// ---------- K2: tmax, E/c (16 rows), rank 16 keys + ki-count 16 rows ----------
__global__ __launch_bounds__(256) void k_mid(const float* __restrict__ s,
                                             const float* __restrict__ t,
                                             float* __restrict__ E1,
                                             float* __restrict__ E2,
                                             float* __restrict__ c1,
                                             float* __restrict__ c2,
                                             int* __restrict__ perm,
                                             float* __restrict__ Es1,
                                             float* __restrict__ Es2,
                                             int* __restrict__ kidx) {
  __shared__ float lred[4];
  const int b = blockIdx.x, tid = threadIdx.x;
  const int wid = tid >> 6, lane = tid & 63;
  float m = -1e30f;
#pragma unroll
  for (int q = 0; q < 8; ++q) {
    int idx = (q * 256 + tid) * 4;
    f4 v = *reinterpret_cast<const f4*>(&t[idx]);
    m = fmaxf(m, fmaxf(fmaxf(v.x, v.y), fmaxf(v.z, v.w)));
  }
  for (int off = 32; off > 0; off >>= 1) m = fmaxf(m, __shfl_down(m, off));
  if (lane == 0) lred[wid] = m;
  __syncthreads();
  float tmax = fmaxf(fmaxf(lred[0], lred[1]), fmaxf(lred[2], lred[3]));

  if (tid < 16) {
    int i = b * 16 + tid;
    float ti = t[i];
    E1[i] = expf(ti);
    E2[i] = expf(0.2f * ti);
    float si = s[i];
    float e = si + tmax;
    float mm = e > 0.f ? e : 0.2f * e;
    c1[i] = expf(si - mm);
    c2[i] = expf(0.2f * si - mm);
  }

  // rank 16 keys/block, 4 per wave (wave-uniform keys, per-lane value slices)
  float tkv[4], skv[4]; int jj[4], cnt[4], cntk[4];
#pragma unroll
  for (int q = 0; q < 4; ++q) {
    jj[q] = b * 16 + wid * 4 + q;
    tkv[q] = t[jj[q]];
    skv[q] = -s[jj[q]];
    cnt[q] = 0;
    cntk[q] = 0;
  }
  for (int m2 = 0; m2 < 32; ++m2) {
    int i4 = m2 * 64 + lane;
    f4 v = *reinterpret_cast<const f4*>(&t[i4 * 4]);
    int base = i4 * 4;
#pragma unroll
    for (int q = 0; q < 4; ++q) {
      cnt[q] += (v.x < tkv[q]) || (v.x == tkv[q] && base + 0 < jj[q]);
      cnt[q] += (v.y < tkv[q]) || (v.y == tkv[q] && base + 1 < jj[q]);
      cnt[q] += (v.z < tkv[q]) || (v.z == tkv[q] && base + 2 < jj[q]);
      cnt[q] += (v.w < tkv[q]) || (v.w == tkv[q] && base + 3 < jj[q]);
      cntk[q] += (v.x <= skv[q]) + (v.y <= skv[q]) + (v.z <= skv[q]) + (v.w <= skv[q]);
    }
  }
#pragma unroll
  for (int q = 0; q < 4; ++q) {
    int c = cnt[q], ck = cntk[q];
    for (int off = 32; off > 0; off >>= 1) {
      c += __shfl_down(c, off);
      ck += __shfl_down(ck, off);
    }
    if (lane == 0) {
      perm[c] = jj[q];
      Es1[c] = expf(tkv[q]);        // bitwise == E1[jj[q]]
      Es2[c] = expf(0.2f * tkv[q]);
      kidx[jj[q]] = ck;
    }
  }
}

// ---------- K3: per-chunk totals of Es*H(perm) over sorted order ----------
__global__ __launch_bounds__(256) void k_chunk(const float* __restrict__ H,
                                               const float* __restrict__ Es1,
                                               const float* __restrict__ Es2,
                                               const int* __restrict__ perm,
                                               float* __restrict__ Ctot1,
                                               float* __restrict__ Ctot2,
                                               float* __restrict__ cs1,
                                               float* __restrict__ cs2) {
  __shared__ int pms[CS];
  int c = blockIdx.x;
  int d = threadIdx.x;
  if (d < CS) pms[d] = perm[c * CS + d];
  __syncthreads();
  float s1 = 0.f, s2 = 0.f, a1 = 0.f, a2 = 0.f;
#pragma unroll 4
  for (int kk = 0; kk < CS; ++kk) {
    int mI = c * CS + kk;
    float e1 = Es1[mI], e2 = Es2[mI];
    float h = H[(size_t)pms[kk] * DD + d];
    s1 += e1 * h; s2 += e2 * h;
    a1 += e1;     a2 += e2;
  }
  Ctot1[c * DD + d] = s1;
  Ctot2[c * DD + d] = s2;
  if (d == 0) { cs1[c] = a1; cs2[c] = a2; }
}

// ---------- K4: Cpre (triangular, pipelined) + scalar scan + f1/f2 ----------
__global__ __launch_bounds__(256) void k_scan(const float* __restrict__ Ctot1,
                                              const float* __restrict__ Ctot2,
                                              const float* __restrict__ cs1,
                                              const float* __restrict__ cs2,
                                              const float* __restrict__ Es1,
                                              const float* __restrict__ Es2,
                                              const int* __restrict__ kidx,
                                              const float* __restrict__ c1,
                                              const float* __restrict__ c2,
                                              float* __restrict__ Cpre1,
                                              float* __restrict__ Cpre2,
                                              float* __restrict__ f1,
                                              float* __restrict__ f2) {
  __shared__ float sc1[NC], sc2[NC];
  const int c = blockIdx.x;
  const int d = threadIdx.x;
  float r1a = 0.f, r1b = 0.f, r2a = 0.f, r2b = 0.f;
  int cc = 0;
  for (; cc + 4 <= c; cc += 4) {
    r1a += Ctot1[(cc + 0) * DD + d];
    r1b += Ctot1[(cc + 1) * DD + d];
    r1a += Ctot1[(cc + 2) * DD + d];
    r1b += Ctot1[(cc + 3) * DD + d];
    r2a += Ctot2[(cc + 0) * DD + d];
    r2b += Ctot2[(cc + 1) * DD + d];
    r2a += Ctot2[(cc + 2) * DD + d];
    r2b += Ctot2[(cc + 3) * DD + d];
  }
  for (; cc < c; ++cc) {
    r1a += Ctot1[cc * DD + d];
    r2a += Ctot2[cc * DD + d];
  }
  float r1 = r1a + r1b, r2 = r2a + r2b;
  Cpre1[(size_t)c * DD + d] = r1;
  Cpre2[(size_t)c * DD + d] = r2;
  if (c == NC - 1) {
    Cpre1[(size_t)NC * DD + d] = r1 + Ctot1[c * DD + d];
    Cpre2[(size_t)NC * DD + d] = r2 + Ctot2[c * DD + d];
  }
  sc1[d] = cs1[d];
  sc2[d] = cs2[d];
  __syncthreads();
  for (int off = 1; off < NC; off <<= 1) {
    float y1 = (d >= off) ? sc1[d - off] : 0.f;
    float y2 = (d >= off) ? sc2[d - off] : 0.f;
    __syncthreads();
    sc1[d] += y1; sc2[d] += y2;
    __syncthreads();
  }
  if (d < 32) {
    int i = c * 32 + d;
    int ki = kidx[i];
    int ci = ki >> 5;
    float sp1 = ci ? sc1[ci - 1] : 0.f;
    float sp2 = ci ? sc2[ci - 1] : 0.f;
    for (int m = ci * CS; m < ki; ++m) { sp1 += Es1[m]; sp2 += Es2[m]; }
    float T1s = sc1[NC - 1];
    float a1 = c1[i], a2 = c2[i];
    float Z = a1 * (T1s - sp1) + a2 * sp2;
    float rZ = 1.0f / Z;
    f1[i] = rZ * a1;
    f2[i] = rZ * a2;
  }
}

// ---- shared fin core: 4 rows starting at i0 ----
__device__ __forceinline__ void fin_rows(int i0, int d,
                                         const int* __restrict__ kidx,
                                         const float* __restrict__ Es1,
                                         const float* __restrict__ Es2,
                                         const int* __restrict__ perm,
                                         const float* __restrict__ H,
                                         const float* __restrict__ Cpre1,
                                         const float* __restrict__ Cpre2,
                                         const float* __restrict__ f1,
                                         const float* __restrict__ f2,
                                         float* __restrict__ out) {
  float T1 = Cpre1[(size_t)NC * DD + d];
#pragma unroll
  for (int r = 0; r < 4; ++r) {
    int i = i0 + r;
    int ki = kidx[i];
    int ci = ki >> 5;
    float P1 = Cpre1[(size_t)ci * DD + d];
    float P2 = Cpre2[(size_t)ci * DD + d];
    for (int m = ci * CS; m < ki; ++m) {
      float h = H[(size_t)perm[m] * DD + d];
      P1 += Es1[m] * h;
      P2 += Es2[m] * h;
    }
    out[(size_t)i * DD + d] = f1[i] * (T1 - P1) + f2[i] * P2;
  }
}

// ---- shared astream core: 32 rows x 1024 cols ----
__device__ __forceinline__ void astream_tile(int i0, int j0,
                                             const float* __restrict__ s,
                                             const float* __restrict__ t,
                                             const float* __restrict__ E1,
                                             const float* __restrict__ E2,
                                             const float* __restrict__ f1,
                                             const float* __restrict__ f2,
                                             float* __restrict__ A) {
  f4 t4  = *reinterpret_cast<const f4*>(&t[j0]);
  f4 e14 = *reinterpret_cast<const f4*>(&E1[j0]);
  f4 e24 = *reinterpret_cast<const f4*>(&E2[j0]);
#pragma unroll 4
  for (int rr = 0; rr < 32; ++rr) {
    int i = i0 + rr;
    float ss = s[i], ff1 = f1[i], ff2 = f2[i];
    f4v o;
    float e;
    e = ss + t4.x; o.x = (e > 0.f) ? ff1 * e14.x : ff2 * e24.x;
    e = ss + t4.y; o.y = (e > 0.f) ? ff1 * e14.y : ff2 * e24.y;
    e = ss + t4.z; o.z = (e > 0.f) ? ff1 * e14.z : ff2 * e24.z;
    e = ss + t4.w; o.w = (e > 0.f) ? ff1 * e14.w : ff2 * e24.w;
    __builtin_nontemporal_store(o, reinterpret_cast<f4v*>(&A[(size_t)i * NN + j0]));
  }
}

// ---------- K5 (fast path): merged finalize + A-stream, 2048 blocks ----------
__global__ __launch_bounds__(256) void k_finstream(const int* __restrict__ kidx,
                                                   const float* __restrict__ Es1,
                                                   const float* __restrict__ Es2,
                                                   const int* __restrict__ perm,
                                                   const float* __restrict__ H,
                                                   const float* __restrict__ Cpre1,
                                                   const float* __restrict__ Cpre2,
                                                   const float* __restrict__ f1,
                                                   const float* __restrict__ f2,
                                                   float* __restrict__ out,
                                                   const float* __restrict__ s,
                                                   const float* __restrict__ t,
                                                   const float* __restrict__ E1,
                                                   const float* __restrict__ E2,
                                                   float* __restrict__ A) {
  const int bb = blockIdx.x;
  const int d = threadIdx.x;
  fin_rows(bb * 4, d, kidx, Es1, Es2, perm, H, Cpre1, Cpre2, f1, f2, out);
  astream_tile((bb >> 3) * 32, (bb & 7) * 1024 + d * 4, s, t, E1, E2, f1, f2, A);
}

// ---------- fallback path kernels ----------
__global__ __launch_bounds__(256) void k_fin2(const int* __restrict__ kidx,
                                              const float* __restrict__ Es1,
                                              const float* __restrict__ Es2,
                                              const int* __restrict__ perm,
                                              const float* __restrict__ H,
                                              const float* __restrict__ Cpre1,
                                              const float* __restrict__ Cpre2,
                                              const float* __restrict__ f1,
                                              const float* __restrict__ f2,
                                              float* __restrict__ out) {
  fin_rows(blockIdx.x * 4, threadIdx.x, kidx, Es1, Es2, perm, H, Cpre1, Cpre2,
           f1, f2, out);
}

__global__ __launch_bounds__(256) void k_astream(const float* __restrict__ s,
                                                 const float* __restrict__ t,
                                                 const float* __restrict__ E1,
                                                 const float* __restrict__ E2,
                                                 const float* __restrict__ f1,
                                                 const float* __restrict__ f2,
                                                 float* __restrict__ A) {
  astream_tile(blockIdx.y * 32, blockIdx.x * 1024 + threadIdx.x * 4,
               s, t, E1, E2, f1, f2, A);
}

extern "C" void kernel_launch(void* const* d_in, const int* in_sizes, int n_in,
                              void* d_out, int out_size, void* d_ws, size_t ws_size,
                              hipStream_t stream) {
  const float* X  = (const float*)d_in[0];
  const float* W  = (const float*)d_in[1];
  const float* av = (const float*)d_in[2];
  float* outp = (float*)d_out;                  // [NN*DD]
  float* A = outp + (size_t)NN * DD;            // [NN*NN]
  float* wsp = (float*)d_ws;

  // common small vectors in ws (first 256 KB)
  float* s  = wsp + 0 * NN;
  float* t  = wsp + 1 * NN;
  float* E1 = wsp + 2 * NN;
  float* E2 = wsp + 3 * NN;
  float* c1 = wsp + 4 * NN;
  float* c2 = wsp + 5 * NN;
  float* f1 = wsp + 6 * NN;
  float* f2 = wsp + 7 * NN;

  // fast path needs scratch + H fully inside ws (so nothing lives in A and
  // the merged fin+astream kernel can run without ordering hazards)
  const size_t FAST_WS_FLOATS = 393216 + (size_t)NN * DD;  // ~9.96 MB
  if (ws_size >= FAST_WS_FLOATS * sizeof(float)) {
    float* Ctot1 = wsp + 65536;
    float* Ctot2 = wsp + 131072;
    float* Cpre1 = wsp + 196608;            // 257*256
    float* Cpre2 = wsp + 262400;
    float* cs1   = wsp + 328192;
    float* cs2   = wsp + 328448;
    float* Es1   = wsp + 328704;
    float* Es2   = wsp + 336896;
    int*   kidx  = (int*)(wsp + 345088);
    int*   perm  = (int*)(wsp + 353280);
    float* H     = wsp + 393216;            // 2M floats

    k_gemm<<<dim3(NN / 64, DD / 64), 256, 0, stream>>>(X, W, av, H, s, t);
    k_mid<<<NN / 16, 256, 0, stream>>>(s, t, E1, E2, c1, c2, perm, Es1, Es2, kidx);
    k_chunk<<<NC, 256, 0, stream>>>(H, Es1, Es2, perm, Ctot1, Ctot2, cs1, cs2);
    k_scan<<<NC, 256, 0, stream>>>(Ctot1, Ctot2, cs1, cs2, Es1, Es2, kidx, c1, c2,
                                   Cpre1, Cpre2, f1, f2);
    k_finstream<<<NN / 4, 256, 0, stream>>>(kidx, Es1, Es2, perm, H, Cpre1, Cpre2,
                                            f1, f2, outp, s, t, E1, E2, A);
  } else {
    // fallback: scratch in A-region (R10 structure)
    float* Ctot1 = A;
    float* Ctot2 = A + 65536;
    float* Cpre1 = A + 131072;
    float* Cpre2 = A + 196864;
    float* cs1   = A + 262656;
    float* cs2   = A + 262912;
    int*   perm  = (int*)(A + 271360);
    int*   kidx  = (int*)(A + 279552);
    float* Es1   = A + 287744;
    float* Es2   = A + 295936;
    float* H     = A + 16777216;

    k_gemm<<<dim3(NN / 64, DD / 64), 256, 0, stream>>>(X, W, av, H, s, t);
    k_mid<<<NN / 16, 256, 0, stream>>>(s, t, E1, E2, c1, c2, perm, Es1, Es2, kidx);
    k_chunk<<<NC, 256, 0, stream>>>(H, Es1, Es2, perm, Ctot1, Ctot2, cs1, cs2);
    k_scan<<<NC, 256, 0, stream>>>(Ctot1, Ctot2, cs1, cs2, Es1, Es2, kidx, c1, c2,
                                   Cpre1, Cpre2, f1, f2);
    k_fin2<<<NN / 4, 256, 0, stream>>>(kidx, Es1, Es2, perm, H, Cpre1, Cpre2,
                                       f1, f2, outp);
    k_astream<<<dim3(NN / 1024, NN / 32), 256, 0, stream>>>(s, t, E1, E2, f1, f2, A);
  }
}